// Round 9
// baseline (464.098 us; speedup 1.0000x reference)
//
#include <hip/hip_runtime.h>
#include <hip/hip_bf16.h>
#include <hip/hip_cooperative_groups.h>

namespace cg = cooperative_groups;

#define NCH 64
#define SPAN 64            // dst nodes per bucket (dl fits in 6 bits)
#define MEGA_THREADS 512
#define NB_CAP 1536        // staged edges per bucket in bucket_node

// ---------------------------------------------------------------------------
// Mega-kernel, phase-selectable.
//   phase == -1 : cooperative run, all phases, grid.sync() between them.
//   phase == k  : run only phase k (fallback: 4 ordinary stream launches,
//                 identical to the proven round-7 pipeline).
// Phases: 0 = zero gcnt + dtype detect; 1 = hist (blocks [0,hb)) || gemm;
//         2 = bucket scan (block 0); 3 = binning (all blocks).
// All phase math is gridDim.x-relative (round-8 lesson: a hard-coded coop
// grid == exact residency capacity can deadlock grid.sync -> GPU hang).
// __launch_bounds__(512,4): round-4 lesson — (512,8) spills w[64] to scratch.
// ---------------------------------------------------------------------------
__global__ __launch_bounds__(MEGA_THREADS, 4)
void mega_kernel(const unsigned short* __restrict__ gp16, int n16,
                 const unsigned* __restrict__ ipw, int niw,
                 unsigned* __restrict__ flags,
                 unsigned* __restrict__ gcnt,
                 unsigned* __restrict__ boffs,
                 unsigned* __restrict__ cursor,
                 unsigned* __restrict__ binned,
                 const void* __restrict__ srcp, const void* __restrict__ dstp,
                 const void* __restrict__ Gp, const void* __restrict__ Rp,
                 const void* __restrict__ Wp, const void* __restrict__ bp,
                 void* __restrict__ PQ,
                 int n_nodes, int n_edges, int nb, int depth, int phase) {
    extern __shared__ unsigned lds[];
    __shared__ unsigned sdet[2];
    __shared__ unsigned sscan[MEGA_THREADS];

    const int tid = threadIdx.x;
    const int bid = blockIdx.x;
    const bool coop = (phase < 0);

    // ---- P0: zero gcnt (all blocks); block 0 detects dtypes ----------------
    if (coop || phase == 0) {
        const int stride = gridDim.x * blockDim.x;
        for (int i = bid * blockDim.x + tid; i < nb; i += stride) gcnt[i] = 0u;
        if (bid == 0) {
            if (tid == 0) { sdet[0] = 0u; sdet[1] = 0u; }
            __syncthreads();
            unsigned le = 0u, lo = 0u;
            // fp32 viewed as shorts: ~12.5% show bf16-exponent >= 0xC0.
            for (int i = tid; i < n16; i += blockDim.x) {
                unsigned ex = (unsigned)((gp16[i] >> 7) & 0xFFu);
                if (ex >= 0xC0u) le++;
            }
            // int64 ids (<2^31): every odd 32-bit word is 0.
            for (int i = tid; i < niw; i += blockDim.x) {
                if ((i & 1) && ipw[i] != 0u) lo++;
            }
            atomicAdd(&sdet[0], le);
            atomicAdd(&sdet[1], lo);
            __syncthreads();
            if (tid == 0) {
                flags[0] = (sdet[0] > 50u) ? 1u : 0u;   // fp32?
                flags[1] = (sdet[1] < 50u) ? 1u : 0u;   // int64?
            }
        }
    }
    if (coop) cg::this_grid().sync();

    // ---- P1: hist (LDS pre-agg) on blocks [0,hb) || edge-MLP GEMM on rest --
    if (coop || phase == 1) {
        const unsigned i64 = flags[1];
        const int hb = (int)(gridDim.x >> 2);            // quarter hist
        if (bid < hb) {
            unsigned* lcnt = lds;
            for (int i = tid; i < nb; i += blockDim.x) lcnt[i] = 0u;
            __syncthreads();
            const int stride = hb * (int)blockDim.x;
            for (int e = bid * (int)blockDim.x + tid; e < n_edges; e += stride) {
                int d = i64 ? (int)((const long long*)dstp)[e]
                            : ((const int*)dstp)[e];
                atomicAdd(&lcnt[d >> 6], 1u);
            }
            __syncthreads();
            for (int i = tid; i < nb; i += blockDim.x)
                if (lcnt[i]) atomicAdd(&gcnt[i], lcnt[i]);
        } else {
            const unsigned f32 = flags[0];
            const int lane = tid & 63;
            const int waveInBlk = tid >> 6;
            const int gwave = (bid - hb) * 8 + waveInBlk;
            const int nwaves = ((int)gridDim.x - hb) * 8;
            const int n_rows = 2 * n_nodes;
            const int ngroups = (n_rows + 3) / 4;

            float* ldsb = (float*)lds;
            float* slot = &ldsb[waveInBlk * 4 * NCH];

            float w[NCH];
            float bias;
            if (f32) {
                const float* Wf = (const float*)Wp;
                #pragma unroll
                for (int k = 0; k < NCH; ++k) w[k] = Wf[lane * NCH + k];
                bias = ((const float*)bp)[lane];
            } else {
                const __hip_bfloat16* Wh = (const __hip_bfloat16*)Wp;
                #pragma unroll
                for (int k = 0; k < NCH; ++k)
                    w[k] = __bfloat162float(Wh[lane * NCH + k]);
                bias = __bfloat162float(((const __hip_bfloat16*)bp)[lane]);
            }

            const int niter = (ngroups + nwaves - 1) / nwaves;
            for (int it = 0; it < niter; ++it) {
                const int grp = gwave + it * nwaves;
                const bool gvalid = (grp < ngroups);
                const int m0 = grp * 4;
                if (gvalid) {
                    const int myrow = m0 + (lane >> 4);
                    const int col = (lane & 15) * 4;
                    float x0 = 0.f, x1 = 0.f, x2 = 0.f, x3 = 0.f;
                    if (myrow < n_rows) {
                        const bool isQ = (myrow >= n_nodes);
                        const int r = isQ ? (myrow - n_nodes) : myrow;
                        const void* inp = isQ ? Rp : Gp;
                        if (f32) {
                            float4 v = *(const float4*)((const float*)inp +
                                                        (size_t)r * NCH + col);
                            x0 = v.x; x1 = v.y; x2 = v.z; x3 = v.w;
                        } else {
                            ushort4 v = *(const ushort4*)(
                                (const unsigned short*)inp + (size_t)r * NCH + col);
                            x0 = __bfloat162float(*(__hip_bfloat16*)&v.x);
                            x1 = __bfloat162float(*(__hip_bfloat16*)&v.y);
                            x2 = __bfloat162float(*(__hip_bfloat16*)&v.z);
                            x3 = __bfloat162float(*(__hip_bfloat16*)&v.w);
                        }
                    }
                    const int sb = (lane >> 4) * NCH + col;
                    slot[sb + 0] = x0; slot[sb + 1] = x1;
                    slot[sb + 2] = x2; slot[sb + 3] = x3;
                }
                __syncthreads();
                if (gvalid) {
                    #pragma unroll
                    for (int rr = 0; rr < 4; ++rr) {
                        const int m = m0 + rr;
                        if (m < n_rows) {
                            float a0 = 0.f, a1 = 0.f, a2 = 0.f, a3 = 0.f;
                            const float4* r4 = (const float4*)(slot + rr * NCH);
                            #pragma unroll
                            for (int q = 0; q < 16; ++q) {
                                float4 rv = r4[q];
                                a0 = fmaf(rv.x, w[4 * q + 0], a0);
                                a1 = fmaf(rv.y, w[4 * q + 1], a1);
                                a2 = fmaf(rv.z, w[4 * q + 2], a2);
                                a3 = fmaf(rv.w, w[4 * q + 3], a3);
                            }
                            float acc = (a0 + a1) + (a2 + a3);
                            if (m >= n_nodes) acc -= bias;   // Q' = RSC@W^T - b
                            if (f32) ((float*)PQ)[(size_t)m * NCH + lane] = acc;
                            else ((__hip_bfloat16*)PQ)[(size_t)m * NCH + lane] =
                                     __float2bfloat16(acc);
                        }
                    }
                }
                __syncthreads();
            }
        }
    }
    if (coop) cg::this_grid().sync();

    // ---- P2: exclusive scan over nb bucket counts (block 0 only) ----------
    if (coop || phase == 2) {
        if (bid == 0) {
            const int L = (nb + MEGA_THREADS - 1) / MEGA_THREADS;
            unsigned local = 0u;
            for (int i = 0; i < L; ++i) {
                int idx = tid * L + i;
                if (idx < nb) local += gcnt[idx];
            }
            sscan[tid] = local;
            __syncthreads();
            for (int off = 1; off < MEGA_THREADS; off <<= 1) {
                unsigned v = (tid >= off) ? sscan[tid - off] : 0u;
                __syncthreads();
                sscan[tid] += v;
                __syncthreads();
            }
            unsigned run = sscan[tid] - local;
            for (int i = 0; i < L; ++i) {
                int idx = tid * L + i;
                if (idx < nb) {
                    boffs[idx] = run; cursor[idx] = run; run += gcnt[idx];
                }
            }
        }
    }
    if (coop) cg::this_grid().sync();

    // ---- P3: binning on ALL blocks ----------------------------------------
    if (coop || phase == 3) {
        const unsigned i64 = flags[1];
        unsigned* lcnt = lds;
        unsigned* stage = lds + nb;
        for (int i = tid; i < nb; i += blockDim.x) lcnt[i] = 0u;
        __syncthreads();
        const int chunk = (n_edges + (int)gridDim.x - 1) / (int)gridDim.x;
        const int e0 = bid * chunk;
        const int e1 = min(e0 + chunk, n_edges);
        for (int e = e0 + tid; e < e1; e += blockDim.x) {
            int s, d;
            if (i64) {
                s = (int)((const long long*)srcp)[e];
                d = (int)((const long long*)dstp)[e];
            } else {
                s = ((const int*)srcp)[e];
                d = ((const int*)dstp)[e];
            }
            const int bkt = d >> 6;
            const unsigned pk = ((unsigned)(d & 63) << 26) | (unsigned)s;
            unsigned pos = atomicAdd(&lcnt[bkt], 1u);
            if ((int)pos < depth) {
                stage[bkt * depth + (int)pos] = pk;
            } else {
                unsigned g = atomicAdd(&cursor[bkt], 1u);
                binned[g] = pk;
            }
        }
        __syncthreads();
        for (int bkt = tid; bkt < nb; bkt += blockDim.x) {
            int k = min((int)lcnt[bkt], depth);
            if (k > 0) {
                unsigned base = atomicAdd(&cursor[bkt], (unsigned)k);
                for (int i = 0; i < k; ++i)
                    binned[base + i] = stage[bkt * depth + i];
            }
        }
    }
}

// ---------------------------------------------------------------------------
// FUSED bucket sort + node aggregation (round-7 winner, unchanged):
// block = bucket of 64 dst nodes. Stage packed edges in LDS, in-LDS counting
// sort into per-node runs, then wave-per-node gather with register
// accumulation (NO LDS accumulators — round-1 lesson). Overflow (>NB_CAP)
// falls back to a per-node filter scan over global binned (rare).
// ---------------------------------------------------------------------------
__global__ __launch_bounds__(512)
void bucket_node_kernel(const unsigned* __restrict__ binned,
                        const unsigned* __restrict__ boffs,
                        const unsigned* __restrict__ gcnt,
                        const void* __restrict__ PQ,
                        const unsigned* __restrict__ flags,
                        void* __restrict__ outp, int n_nodes) {
    __shared__ unsigned scnt[SPAN];
    __shared__ unsigned soff[SPAN];
    __shared__ unsigned cur[SPAN];
    __shared__ unsigned dext[SPAN];
    __shared__ unsigned stage[NB_CAP];
    __shared__ unsigned sorted[NB_CAP];

    const int b = blockIdx.x;
    const int tid = threadIdx.x;
    const int estart = (int)boffs[b];
    const int count = (int)gcnt[b];
    const int lim = (count < NB_CAP) ? count : NB_CAP;

    if (tid < SPAN) { scnt[tid] = 0u; dext[tid] = 0u; }
    __syncthreads();

    for (int i = tid; i < count; i += 512) {
        const unsigned pk = binned[estart + i];
        if (i < NB_CAP) { stage[i] = pk; atomicAdd(&scnt[pk >> 26], 1u); }
        else atomicAdd(&dext[pk >> 26], 1u);
    }
    __syncthreads();

    if (tid == 0) {
        unsigned run = 0u;
        #pragma unroll
        for (int i = 0; i < SPAN; ++i) { soff[i] = run; cur[i] = run; run += scnt[i]; }
    }
    __syncthreads();

    for (int i = tid; i < lim; i += 512) {
        const unsigned pk = stage[i];
        const unsigned pos = atomicAdd(&cur[pk >> 26], 1u);
        sorted[pos] = pk & 0x03FFFFFFu;
    }
    __syncthreads();

    const unsigned f32 = flags[0];
    const int lane = tid & 63;
    const int wid = tid >> 6;
    const float* Pf = (const float*)PQ;
    const unsigned short* Ph = (const unsigned short*)PQ;

    for (int nn = wid; nn < SPAN; nn += 8) {
        const int n = b * SPAN + nn;
        if (n >= n_nodes) break;
        float q;
        if (f32) q = Pf[(size_t)(n_nodes + n) * NCH + lane];
        else {
            unsigned short h = Ph[(size_t)(n_nodes + n) * NCH + lane];
            q = __bfloat162float(*(__hip_bfloat16*)&h);
        }
        const int s0i = (int)soff[nn];
        const int scn = (int)scnt[nn];
        float vmax = 0.0f, vsum = 0.0f;
        int j = 0;
        for (; j + 4 <= scn; j += 4) {
            const int e0 = (int)sorted[s0i + j];
            const int e1 = (int)sorted[s0i + j + 1];
            const int e2 = (int)sorted[s0i + j + 2];
            const int e3 = (int)sorted[s0i + j + 3];
            float p0, p1, p2, p3;
            if (f32) {
                p0 = Pf[(size_t)e0 * NCH + lane];
                p1 = Pf[(size_t)e1 * NCH + lane];
                p2 = Pf[(size_t)e2 * NCH + lane];
                p3 = Pf[(size_t)e3 * NCH + lane];
            } else {
                unsigned short h0 = Ph[(size_t)e0 * NCH + lane];
                unsigned short h1 = Ph[(size_t)e1 * NCH + lane];
                unsigned short h2 = Ph[(size_t)e2 * NCH + lane];
                unsigned short h3 = Ph[(size_t)e3 * NCH + lane];
                p0 = __bfloat162float(*(__hip_bfloat16*)&h0);
                p1 = __bfloat162float(*(__hip_bfloat16*)&h1);
                p2 = __bfloat162float(*(__hip_bfloat16*)&h2);
                p3 = __bfloat162float(*(__hip_bfloat16*)&h3);
            }
            const float v0 = fmaxf(p0 - q, 0.0f);
            const float v1 = fmaxf(p1 - q, 0.0f);
            const float v2 = fmaxf(p2 - q, 0.0f);
            const float v3 = fmaxf(p3 - q, 0.0f);
            vmax = fmaxf(fmaxf(vmax, v0), fmaxf(v1, fmaxf(v2, v3)));
            vsum += (v0 + v1) + (v2 + v3);
        }
        for (; j < scn; ++j) {
            const int e = (int)sorted[s0i + j];
            float p;
            if (f32) p = Pf[(size_t)e * NCH + lane];
            else {
                unsigned short h = Ph[(size_t)e * NCH + lane];
                p = __bfloat162float(*(__hip_bfloat16*)&h);
            }
            const float v = fmaxf(p - q, 0.0f);
            vmax = fmaxf(vmax, v);
            vsum += v;
        }
        for (int i = NB_CAP; i < count; ++i) {
            const unsigned pk = binned[estart + i];
            if ((int)(pk >> 26) == nn) {
                const int e = (int)(pk & 0x03FFFFFFu);
                float p;
                if (f32) p = Pf[(size_t)e * NCH + lane];
                else {
                    unsigned short h = Ph[(size_t)e * NCH + lane];
                    p = __bfloat162float(*(__hip_bfloat16*)&h);
                }
                const float v = fmaxf(p - q, 0.0f);
                vmax = fmaxf(vmax, v);
                vsum += v;
            }
        }
        const int deg = scn + (int)dext[nn];
        const float avg = vsum / (float)(deg > 0 ? deg : 1);
        if (f32) {
            float* out = (float*)outp;
            out[(size_t)n * 2 * NCH + lane] = vmax;
            out[(size_t)n * 2 * NCH + NCH + lane] = avg;
        } else {
            __hip_bfloat16* out = (__hip_bfloat16*)outp;
            out[(size_t)n * 2 * NCH + lane] = __float2bfloat16(vmax);
            out[(size_t)n * 2 * NCH + NCH + lane] = __float2bfloat16(avg);
        }
    }
}

extern "C" void kernel_launch(void* const* d_in, const int* in_sizes, int n_in,
                              void* d_out, int out_size, void* d_ws, size_t ws_size,
                              hipStream_t stream) {
    const void* G = d_in[0];
    const void* RSC = d_in[1];
    const void* src = d_in[2];
    const void* dst = d_in[3];
    const void* W = d_in[4];
    const void* b = d_in[5];

    const int n_nodes = in_sizes[0] / NCH;
    const int n_edges = in_sizes[2];
    const int nb = (n_nodes + SPAN - 1) / SPAN;

    // ws layout (bytes): [flags 256][binned 4E][boffs 4nb][cursor 4nb]
    //                    [gcnt 4nb][PQ dtype*64*2N]
    char* ws = (char*)d_ws;
    unsigned* flags = (unsigned*)ws;
    size_t off = 256;
    unsigned* binned = (unsigned*)(ws + off);
    off += (((size_t)n_edges * 4 + 255) / 256) * 256;
    unsigned* boffs = (unsigned*)(ws + off);
    off += (((size_t)nb * 4 + 255) / 256) * 256;
    unsigned* cursor = (unsigned*)(ws + off);
    off += (((size_t)nb * 4 + 255) / 256) * 256;
    unsigned* gcnt = (unsigned*)(ws + off);
    off += (((size_t)nb * 4 + 255) / 256) * 256;
    void* PQ = (void*)(ws + off);                   // fp32 or bf16 per flags[0]

    int n_g_probe = (in_sizes[0] < 8192) ? in_sizes[0] : 8192;
    int n_idx_probe = (n_edges < 8192) ? n_edges : 8192;

    // depth sized for ~37.5K LDS.
    int depth = 9728 / nb - 1;
    if (depth > 19) depth = 19;
    if (depth < 4) depth = 4;
    size_t mega_lds = (size_t)nb * (depth + 1) * 4;
    const size_t gemm_lds = (size_t)(MEGA_THREADS / 64) * 4 * NCH * 4;  // 8 KB
    if (mega_lds < gemm_lds) mega_lds = gemm_lds;

    const unsigned short* gp16 = (const unsigned short*)G;
    const unsigned* ipw = (const unsigned*)src;

    // Runtime cooperative capacity (round-8 lesson: never hard-code a coop
    // grid at exact capacity — grid.sync deadlocks -> GPU hang).
    int coop_attr = 0, ncu = 0, maxblk = 0, dev = 0;
    (void)hipGetDevice(&dev);
    (void)hipDeviceGetAttribute(&coop_attr, hipDeviceAttributeCooperativeLaunch,
                                dev);
    (void)hipDeviceGetAttribute(&ncu, hipDeviceAttributeMultiprocessorCount, dev);
    (void)hipOccupancyMaxActiveBlocksPerMultiprocessor(
        &maxblk, (const void*)mega_kernel, MEGA_THREADS, mega_lds);

    int phase_all = -1;
    if (coop_attr && maxblk > 0 && ncu > 0) {
        int cap = maxblk * ncu;
        int grid = (cap < 512) ? cap : 512;
        if (grid >= 8) {
            // leave one block/CU of headroom when capacity is tight
            if (grid == cap && maxblk > 1) grid = cap - ncu;
            if (grid < 8) grid = 8;
            void* args[] = {
                (void*)&gp16, (void*)&n_g_probe, (void*)&ipw, (void*)&n_idx_probe,
                (void*)&flags, (void*)&gcnt, (void*)&boffs, (void*)&cursor,
                (void*)&binned,
                (void*)&src, (void*)&dst,
                (void*)&G, (void*)&RSC, (void*)&W, (void*)&b,
                (void*)&PQ, (void*)&n_nodes, (void*)&n_edges, (void*)&nb,
                (void*)&depth, (void*)&phase_all
            };
            hipError_t err = hipLaunchCooperativeKernel(
                (const void*)mega_kernel, dim3(grid), dim3(MEGA_THREADS), args,
                (unsigned)mega_lds, stream);
            if (err == hipSuccess) {
                bucket_node_kernel<<<nb, 512, 0, stream>>>(
                    binned, boffs, gcnt, PQ, flags, d_out, n_nodes);
                return;
            }
        }
    }

    // ---- Fallback: proven round-7 pipeline via phased launches ------------
    mega_kernel<<<64, MEGA_THREADS, 0, stream>>>(
        gp16, n_g_probe, ipw, n_idx_probe, flags, gcnt, boffs, cursor, binned,
        src, dst, G, RSC, W, b, PQ, n_nodes, n_edges, nb, depth, 0);
    mega_kernel<<<1024, MEGA_THREADS, mega_lds, stream>>>(
        gp16, n_g_probe, ipw, n_idx_probe, flags, gcnt, boffs, cursor, binned,
        src, dst, G, RSC, W, b, PQ, n_nodes, n_edges, nb, depth, 1);
    mega_kernel<<<1, MEGA_THREADS, 0, stream>>>(
        gp16, n_g_probe, ipw, n_idx_probe, flags, gcnt, boffs, cursor, binned,
        src, dst, G, RSC, W, b, PQ, n_nodes, n_edges, nb, depth, 2);
    mega_kernel<<<512, MEGA_THREADS, mega_lds, stream>>>(
        gp16, n_g_probe, ipw, n_idx_probe, flags, gcnt, boffs, cursor, binned,
        src, dst, G, RSC, W, b, PQ, n_nodes, n_edges, nb, depth, 3);

    bucket_node_kernel<<<nb, 512, 0, stream>>>(binned, boffs, gcnt, PQ, flags,
                                               d_out, n_nodes);
}

// Round 10
// 340.983 us; speedup vs baseline: 1.3611x; 1.3611x over previous
//
#include <hip/hip_runtime.h>
#include <hip/hip_bf16.h>

#define NCH 64
#define SPAN 64            // dst nodes per bucket (dl fits in 6 bits)
#define MEGA_THREADS 512
#define NB_CAP 1536        // staged edges per bucket in bucket_node

// ---------------------------------------------------------------------------
// Mega-kernel, phase-selectable (4 ordinary stream launches — round-9 lesson:
// cooperative grid.sync on MI355X costs ~270us in degraded L2 coherency;
// NEVER fuse phases via coop launch on this chip).
// Phases: 0 = zero gcnt + dtype detect; 1 = hist (blocks [0,gridDim/4)) ||
//         gemm (rest); 2 = bucket scan (block 0); 3 = binning (all blocks).
// __launch_bounds__(512,4): round-4 lesson — (512,8) spills w[64] to scratch.
// ---------------------------------------------------------------------------
__global__ __launch_bounds__(MEGA_THREADS, 4)
void mega_kernel(const unsigned short* __restrict__ gp16, int n16,
                 const unsigned* __restrict__ ipw, int niw,
                 unsigned* __restrict__ flags,
                 unsigned* __restrict__ gcnt,
                 unsigned* __restrict__ boffs,
                 unsigned* __restrict__ cursor,
                 unsigned* __restrict__ binned,
                 const void* __restrict__ srcp, const void* __restrict__ dstp,
                 const void* __restrict__ Gp, const void* __restrict__ Rp,
                 const void* __restrict__ Wp, const void* __restrict__ bp,
                 void* __restrict__ PQ,
                 int n_nodes, int n_edges, int nb, int depth, int phase) {
    extern __shared__ unsigned lds[];
    __shared__ unsigned sdet[2];
    __shared__ unsigned sscan[MEGA_THREADS];

    const int tid = threadIdx.x;
    const int bid = blockIdx.x;

    // ---- P0: zero gcnt (all blocks); block 0 detects dtypes ----------------
    if (phase == 0) {
        const int stride = gridDim.x * blockDim.x;
        for (int i = bid * blockDim.x + tid; i < nb; i += stride) gcnt[i] = 0u;
        if (bid == 0) {
            if (tid == 0) { sdet[0] = 0u; sdet[1] = 0u; }
            __syncthreads();
            unsigned le = 0u, lo = 0u;
            // fp32 viewed as shorts: ~12.5% show bf16-exponent >= 0xC0.
            for (int i = tid; i < n16; i += blockDim.x) {
                unsigned ex = (unsigned)((gp16[i] >> 7) & 0xFFu);
                if (ex >= 0xC0u) le++;
            }
            // int64 ids (<2^31): every odd 32-bit word is 0.
            for (int i = tid; i < niw; i += blockDim.x) {
                if ((i & 1) && ipw[i] != 0u) lo++;
            }
            atomicAdd(&sdet[0], le);
            atomicAdd(&sdet[1], lo);
            __syncthreads();
            if (tid == 0) {
                flags[0] = (sdet[0] > 50u) ? 1u : 0u;   // fp32?
                flags[1] = (sdet[1] < 50u) ? 1u : 0u;   // int64?
            }
        }
    }

    // ---- P1: hist (LDS pre-agg) on blocks [0,hb) || edge-MLP GEMM on rest --
    if (phase == 1) {
        const unsigned i64 = flags[1];
        const int hb = (int)(gridDim.x >> 2);            // quarter hist
        if (bid < hb) {
            unsigned* lcnt = lds;
            for (int i = tid; i < nb; i += blockDim.x) lcnt[i] = 0u;
            __syncthreads();
            const int stride = hb * (int)blockDim.x;
            for (int e = bid * (int)blockDim.x + tid; e < n_edges; e += stride) {
                int d = i64 ? (int)((const long long*)dstp)[e]
                            : ((const int*)dstp)[e];
                atomicAdd(&lcnt[d >> 6], 1u);
            }
            __syncthreads();
            for (int i = tid; i < nb; i += blockDim.x)
                if (lcnt[i]) atomicAdd(&gcnt[i], lcnt[i]);
        } else {
            const unsigned f32 = flags[0];
            const int lane = tid & 63;
            const int waveInBlk = tid >> 6;
            const int gwave = (bid - hb) * 8 + waveInBlk;
            const int nwaves = ((int)gridDim.x - hb) * 8;
            const int n_rows = 2 * n_nodes;
            const int ngroups = (n_rows + 3) / 4;

            float* ldsb = (float*)lds;
            float* slot = &ldsb[waveInBlk * 4 * NCH];

            float w[NCH];
            float bias;
            if (f32) {
                const float* Wf = (const float*)Wp;
                #pragma unroll
                for (int k = 0; k < NCH; ++k) w[k] = Wf[lane * NCH + k];
                bias = ((const float*)bp)[lane];
            } else {
                const __hip_bfloat16* Wh = (const __hip_bfloat16*)Wp;
                #pragma unroll
                for (int k = 0; k < NCH; ++k)
                    w[k] = __bfloat162float(Wh[lane * NCH + k]);
                bias = __bfloat162float(((const __hip_bfloat16*)bp)[lane]);
            }

            const int niter = (ngroups + nwaves - 1) / nwaves;
            for (int it = 0; it < niter; ++it) {
                const int grp = gwave + it * nwaves;
                const bool gvalid = (grp < ngroups);
                const int m0 = grp * 4;
                if (gvalid) {
                    const int myrow = m0 + (lane >> 4);
                    const int col = (lane & 15) * 4;
                    float x0 = 0.f, x1 = 0.f, x2 = 0.f, x3 = 0.f;
                    if (myrow < n_rows) {
                        const bool isQ = (myrow >= n_nodes);
                        const int r = isQ ? (myrow - n_nodes) : myrow;
                        const void* inp = isQ ? Rp : Gp;
                        if (f32) {
                            float4 v = *(const float4*)((const float*)inp +
                                                        (size_t)r * NCH + col);
                            x0 = v.x; x1 = v.y; x2 = v.z; x3 = v.w;
                        } else {
                            ushort4 v = *(const ushort4*)(
                                (const unsigned short*)inp + (size_t)r * NCH + col);
                            x0 = __bfloat162float(*(__hip_bfloat16*)&v.x);
                            x1 = __bfloat162float(*(__hip_bfloat16*)&v.y);
                            x2 = __bfloat162float(*(__hip_bfloat16*)&v.z);
                            x3 = __bfloat162float(*(__hip_bfloat16*)&v.w);
                        }
                    }
                    const int sb = (lane >> 4) * NCH + col;
                    slot[sb + 0] = x0; slot[sb + 1] = x1;
                    slot[sb + 2] = x2; slot[sb + 3] = x3;
                }
                __syncthreads();
                if (gvalid) {
                    #pragma unroll
                    for (int rr = 0; rr < 4; ++rr) {
                        const int m = m0 + rr;
                        if (m < n_rows) {
                            float a0 = 0.f, a1 = 0.f, a2 = 0.f, a3 = 0.f;
                            const float4* r4 = (const float4*)(slot + rr * NCH);
                            #pragma unroll
                            for (int q = 0; q < 16; ++q) {
                                float4 rv = r4[q];
                                a0 = fmaf(rv.x, w[4 * q + 0], a0);
                                a1 = fmaf(rv.y, w[4 * q + 1], a1);
                                a2 = fmaf(rv.z, w[4 * q + 2], a2);
                                a3 = fmaf(rv.w, w[4 * q + 3], a3);
                            }
                            float acc = (a0 + a1) + (a2 + a3);
                            if (m >= n_nodes) acc -= bias;   // Q' = RSC@W^T - b
                            if (f32) ((float*)PQ)[(size_t)m * NCH + lane] = acc;
                            else ((__hip_bfloat16*)PQ)[(size_t)m * NCH + lane] =
                                     __float2bfloat16(acc);
                        }
                    }
                }
                __syncthreads();
            }
        }
    }

    // ---- P2: exclusive scan over nb bucket counts (block 0 only) ----------
    if (phase == 2) {
        if (bid == 0) {
            const int L = (nb + MEGA_THREADS - 1) / MEGA_THREADS;
            unsigned local = 0u;
            for (int i = 0; i < L; ++i) {
                int idx = tid * L + i;
                if (idx < nb) local += gcnt[idx];
            }
            sscan[tid] = local;
            __syncthreads();
            for (int off = 1; off < MEGA_THREADS; off <<= 1) {
                unsigned v = (tid >= off) ? sscan[tid - off] : 0u;
                __syncthreads();
                sscan[tid] += v;
                __syncthreads();
            }
            unsigned run = sscan[tid] - local;
            for (int i = 0; i < L; ++i) {
                int idx = tid * L + i;
                if (idx < nb) {
                    boffs[idx] = run; cursor[idx] = run; run += gcnt[idx];
                }
            }
        }
    }

    // ---- P3: binning on ALL blocks (dedicated full machine) ----------------
    if (phase == 3) {
        const unsigned i64 = flags[1];
        unsigned* lcnt = lds;
        unsigned* stage = lds + nb;
        for (int i = tid; i < nb; i += blockDim.x) lcnt[i] = 0u;
        __syncthreads();
        const int chunk = (n_edges + (int)gridDim.x - 1) / (int)gridDim.x;
        const int e0 = bid * chunk;
        const int e1 = min(e0 + chunk, n_edges);
        for (int e = e0 + tid; e < e1; e += blockDim.x) {
            int s, d;
            if (i64) {
                s = (int)((const long long*)srcp)[e];
                d = (int)((const long long*)dstp)[e];
            } else {
                s = ((const int*)srcp)[e];
                d = ((const int*)dstp)[e];
            }
            const int bkt = d >> 6;
            const unsigned pk = ((unsigned)(d & 63) << 26) | (unsigned)s;
            unsigned pos = atomicAdd(&lcnt[bkt], 1u);
            if ((int)pos < depth) {
                stage[bkt * depth + (int)pos] = pk;
            } else {
                unsigned g = atomicAdd(&cursor[bkt], 1u);
                binned[g] = pk;
            }
        }
        __syncthreads();
        for (int bkt = tid; bkt < nb; bkt += blockDim.x) {
            int k = min((int)lcnt[bkt], depth);
            if (k > 0) {
                unsigned base = atomicAdd(&cursor[bkt], (unsigned)k);
                for (int i = 0; i < k; ++i)
                    binned[base + i] = stage[bkt * depth + i];
            }
        }
    }
}

// ---------------------------------------------------------------------------
// FUSED bucket sort + node aggregation (round-7 winner, unchanged):
// block = bucket of 64 dst nodes. Stage packed edges in LDS, in-LDS counting
// sort into per-node runs, then wave-per-node gather with register
// accumulation (NO LDS accumulators — round-1 lesson). Overflow (>NB_CAP)
// falls back to a per-node filter scan over global binned (rare).
// ---------------------------------------------------------------------------
__global__ __launch_bounds__(512)
void bucket_node_kernel(const unsigned* __restrict__ binned,
                        const unsigned* __restrict__ boffs,
                        const unsigned* __restrict__ gcnt,
                        const void* __restrict__ PQ,
                        const unsigned* __restrict__ flags,
                        void* __restrict__ outp, int n_nodes) {
    __shared__ unsigned scnt[SPAN];
    __shared__ unsigned soff[SPAN];
    __shared__ unsigned cur[SPAN];
    __shared__ unsigned dext[SPAN];
    __shared__ unsigned stage[NB_CAP];
    __shared__ unsigned sorted[NB_CAP];

    const int b = blockIdx.x;
    const int tid = threadIdx.x;
    const int estart = (int)boffs[b];
    const int count = (int)gcnt[b];
    const int lim = (count < NB_CAP) ? count : NB_CAP;

    if (tid < SPAN) { scnt[tid] = 0u; dext[tid] = 0u; }
    __syncthreads();

    for (int i = tid; i < count; i += 512) {
        const unsigned pk = binned[estart + i];
        if (i < NB_CAP) { stage[i] = pk; atomicAdd(&scnt[pk >> 26], 1u); }
        else atomicAdd(&dext[pk >> 26], 1u);
    }
    __syncthreads();

    if (tid == 0) {
        unsigned run = 0u;
        #pragma unroll
        for (int i = 0; i < SPAN; ++i) { soff[i] = run; cur[i] = run; run += scnt[i]; }
    }
    __syncthreads();

    for (int i = tid; i < lim; i += 512) {
        const unsigned pk = stage[i];
        const unsigned pos = atomicAdd(&cur[pk >> 26], 1u);
        sorted[pos] = pk & 0x03FFFFFFu;
    }
    __syncthreads();

    const unsigned f32 = flags[0];
    const int lane = tid & 63;
    const int wid = tid >> 6;
    const float* Pf = (const float*)PQ;
    const unsigned short* Ph = (const unsigned short*)PQ;

    for (int nn = wid; nn < SPAN; nn += 8) {
        const int n = b * SPAN + nn;
        if (n >= n_nodes) break;
        float q;
        if (f32) q = Pf[(size_t)(n_nodes + n) * NCH + lane];
        else {
            unsigned short h = Ph[(size_t)(n_nodes + n) * NCH + lane];
            q = __bfloat162float(*(__hip_bfloat16*)&h);
        }
        const int s0i = (int)soff[nn];
        const int scn = (int)scnt[nn];
        float vmax = 0.0f, vsum = 0.0f;
        int j = 0;
        for (; j + 4 <= scn; j += 4) {
            const int e0 = (int)sorted[s0i + j];
            const int e1 = (int)sorted[s0i + j + 1];
            const int e2 = (int)sorted[s0i + j + 2];
            const int e3 = (int)sorted[s0i + j + 3];
            float p0, p1, p2, p3;
            if (f32) {
                p0 = Pf[(size_t)e0 * NCH + lane];
                p1 = Pf[(size_t)e1 * NCH + lane];
                p2 = Pf[(size_t)e2 * NCH + lane];
                p3 = Pf[(size_t)e3 * NCH + lane];
            } else {
                unsigned short h0 = Ph[(size_t)e0 * NCH + lane];
                unsigned short h1 = Ph[(size_t)e1 * NCH + lane];
                unsigned short h2 = Ph[(size_t)e2 * NCH + lane];
                unsigned short h3 = Ph[(size_t)e3 * NCH + lane];
                p0 = __bfloat162float(*(__hip_bfloat16*)&h0);
                p1 = __bfloat162float(*(__hip_bfloat16*)&h1);
                p2 = __bfloat162float(*(__hip_bfloat16*)&h2);
                p3 = __bfloat162float(*(__hip_bfloat16*)&h3);
            }
            const float v0 = fmaxf(p0 - q, 0.0f);
            const float v1 = fmaxf(p1 - q, 0.0f);
            const float v2 = fmaxf(p2 - q, 0.0f);
            const float v3 = fmaxf(p3 - q, 0.0f);
            vmax = fmaxf(fmaxf(vmax, v0), fmaxf(v1, fmaxf(v2, v3)));
            vsum += (v0 + v1) + (v2 + v3);
        }
        for (; j < scn; ++j) {
            const int e = (int)sorted[s0i + j];
            float p;
            if (f32) p = Pf[(size_t)e * NCH + lane];
            else {
                unsigned short h = Ph[(size_t)e * NCH + lane];
                p = __bfloat162float(*(__hip_bfloat16*)&h);
            }
            const float v = fmaxf(p - q, 0.0f);
            vmax = fmaxf(vmax, v);
            vsum += v;
        }
        for (int i = NB_CAP; i < count; ++i) {
            const unsigned pk = binned[estart + i];
            if ((int)(pk >> 26) == nn) {
                const int e = (int)(pk & 0x03FFFFFFu);
                float p;
                if (f32) p = Pf[(size_t)e * NCH + lane];
                else {
                    unsigned short h = Ph[(size_t)e * NCH + lane];
                    p = __bfloat162float(*(__hip_bfloat16*)&h);
                }
                const float v = fmaxf(p - q, 0.0f);
                vmax = fmaxf(vmax, v);
                vsum += v;
            }
        }
        const int deg = scn + (int)dext[nn];
        const float avg = vsum / (float)(deg > 0 ? deg : 1);
        if (f32) {
            float* out = (float*)outp;
            out[(size_t)n * 2 * NCH + lane] = vmax;
            out[(size_t)n * 2 * NCH + NCH + lane] = avg;
        } else {
            __hip_bfloat16* out = (__hip_bfloat16*)outp;
            out[(size_t)n * 2 * NCH + lane] = __float2bfloat16(vmax);
            out[(size_t)n * 2 * NCH + NCH + lane] = __float2bfloat16(avg);
        }
    }
}

extern "C" void kernel_launch(void* const* d_in, const int* in_sizes, int n_in,
                              void* d_out, int out_size, void* d_ws, size_t ws_size,
                              hipStream_t stream) {
    const void* G = d_in[0];
    const void* RSC = d_in[1];
    const void* src = d_in[2];
    const void* dst = d_in[3];
    const void* W = d_in[4];
    const void* b = d_in[5];

    const int n_nodes = in_sizes[0] / NCH;
    const int n_edges = in_sizes[2];
    const int nb = (n_nodes + SPAN - 1) / SPAN;

    // ws layout (bytes): [flags 256][binned 4E][boffs 4nb][cursor 4nb]
    //                    [gcnt 4nb][PQ dtype*64*2N]
    char* ws = (char*)d_ws;
    unsigned* flags = (unsigned*)ws;
    size_t off = 256;
    unsigned* binned = (unsigned*)(ws + off);
    off += (((size_t)n_edges * 4 + 255) / 256) * 256;
    unsigned* boffs = (unsigned*)(ws + off);
    off += (((size_t)nb * 4 + 255) / 256) * 256;
    unsigned* cursor = (unsigned*)(ws + off);
    off += (((size_t)nb * 4 + 255) / 256) * 256;
    unsigned* gcnt = (unsigned*)(ws + off);
    off += (((size_t)nb * 4 + 255) / 256) * 256;
    void* PQ = (void*)(ws + off);                   // fp32 or bf16 per flags[0]

    int n_g_probe = (in_sizes[0] < 8192) ? in_sizes[0] : 8192;
    int n_idx_probe = (n_edges < 8192) ? n_edges : 8192;

    // depth sized for ~37.5K LDS.
    int depth = 9728 / nb - 1;
    if (depth > 19) depth = 19;
    if (depth < 4) depth = 4;
    size_t mega_lds = (size_t)nb * (depth + 1) * 4;
    const size_t gemm_lds = (size_t)(MEGA_THREADS / 64) * 4 * NCH * 4;  // 8 KB
    if (mega_lds < gemm_lds) mega_lds = gemm_lds;

    const unsigned short* gp16 = (const unsigned short*)G;
    const unsigned* ipw = (const unsigned*)src;

    // Phased launches (round-9 lesson: cooperative grid.sync = ~270us L2
    // coherency tax on MI355X; ordinary stream ordering is the cheap sync).
    mega_kernel<<<64, MEGA_THREADS, 0, stream>>>(
        gp16, n_g_probe, ipw, n_idx_probe, flags, gcnt, boffs, cursor, binned,
        src, dst, G, RSC, W, b, PQ, n_nodes, n_edges, nb, depth, 0);
    mega_kernel<<<1024, MEGA_THREADS, mega_lds, stream>>>(
        gp16, n_g_probe, ipw, n_idx_probe, flags, gcnt, boffs, cursor, binned,
        src, dst, G, RSC, W, b, PQ, n_nodes, n_edges, nb, depth, 1);
    mega_kernel<<<1, MEGA_THREADS, 0, stream>>>(
        gp16, n_g_probe, ipw, n_idx_probe, flags, gcnt, boffs, cursor, binned,
        src, dst, G, RSC, W, b, PQ, n_nodes, n_edges, nb, depth, 2);
    mega_kernel<<<512, MEGA_THREADS, mega_lds, stream>>>(
        gp16, n_g_probe, ipw, n_idx_probe, flags, gcnt, boffs, cursor, binned,
        src, dst, G, RSC, W, b, PQ, n_nodes, n_edges, nb, depth, 3);

    bucket_node_kernel<<<nb, 512, 0, stream>>>(binned, boffs, gcnt, PQ, flags,
                                               d_out, n_nodes);
}

// Round 11
// 184.308 us; speedup vs baseline: 2.5181x; 1.8501x over previous
//
#include <hip/hip_runtime.h>
#include <hip/hip_bf16.h>

#define NCH 64
#define SPAN 64            // dst nodes per bucket (dl fits in 6 bits)
#define HIST_BLOCKS 256
#define HIST_THREADS 1024
#define NBIN 256           // binning blocks (fused kernel, low half)
#define NGEMM 768          // gemm blocks   (fused kernel, high half)
#define FUSE_THREADS 512   // 8 waves/block
#define NB_CAP 1536        // staged edges per bucket in bucket_node

// ---------------------------------------------------------------------------
// Block 0: dtype detection (flags[0]=fp32?, flags[1]=int64?) + zero the
// hist-completion counter flags[2]. Other blocks: zero gcnt (ws poisoned).
// ---------------------------------------------------------------------------
__global__ void detect_init_kernel(const unsigned short* __restrict__ gp, int n16,
                                   const unsigned* __restrict__ ip, int niw,
                                   unsigned* __restrict__ flags,
                                   unsigned* __restrict__ gcnt, int nb) {
    if (blockIdx.x == 0) {
        __shared__ unsigned se, so;
        if (threadIdx.x == 0) { se = 0u; so = 0u; flags[2] = 0u; }
        __syncthreads();
        unsigned le = 0u, lo = 0u;
        // fp32 viewed as shorts: ~12.5% show "bf16 exponent" >= 0xC0 (|x|>=2^65).
        // Genuine bf16 N(0,1): none.
        for (int i = threadIdx.x; i < n16; i += blockDim.x) {
            unsigned ex = (unsigned)((gp[i] >> 7) & 0xFFu);
            if (ex >= 0xC0u) le++;
        }
        // int64 ids (<2^31): every odd 32-bit word is 0. int32 ids: not.
        for (int i = threadIdx.x; i < niw; i += blockDim.x) {
            if ((i & 1) && ip[i] != 0u) lo++;
        }
        atomicAdd(&se, le);
        atomicAdd(&so, lo);
        __syncthreads();
        if (threadIdx.x == 0) {
            flags[0] = (se > 50u) ? 1u : 0u;
            flags[1] = (so < 50u) ? 1u : 0u;
        }
    } else {
        const int stride = (gridDim.x - 1) * blockDim.x;
        for (int i = (blockIdx.x - 1) * blockDim.x + threadIdx.x; i < nb; i += stride)
            gcnt[i] = 0u;
    }
}

// ---------------------------------------------------------------------------
// Bucket histogram + LAST-BLOCK SCAN EPILOGUE (round-11: folds the former
// 1-block bucket_scan dispatch in; 5 -> 4 dispatches). Hist: LDS pre-agg,
// one device-scope global atomic per bucket per block. Epilogue: the block
// that finishes last (flags[2] counter, after __threadfence) re-reads gcnt
// via ATOMIC reads (plain loads may hit stale per-XCD L2 — G16) and writes
// the exclusive scan to boffs + cursor.
// ---------------------------------------------------------------------------
__global__ void bucket_hist_kernel(const void* __restrict__ dstp,
                                   unsigned* __restrict__ gcnt,
                                   unsigned* __restrict__ flags,
                                   unsigned* __restrict__ boffs,
                                   unsigned* __restrict__ cursor,
                                   int n_edges, int nb) {
    extern __shared__ unsigned lcnt[];
    __shared__ unsigned s[HIST_THREADS];
    __shared__ unsigned slast;
    for (int i = threadIdx.x; i < nb; i += blockDim.x) lcnt[i] = 0u;
    __syncthreads();
    const unsigned i64 = flags[1];
    const int stride = gridDim.x * blockDim.x;
    for (int e = blockIdx.x * blockDim.x + threadIdx.x; e < n_edges; e += stride) {
        int d = i64 ? (int)((const long long*)dstp)[e] : ((const int*)dstp)[e];
        atomicAdd(&lcnt[d >> 6], 1u);
    }
    __syncthreads();
    for (int i = threadIdx.x; i < nb; i += blockDim.x)
        if (lcnt[i]) atomicAdd(&gcnt[i], lcnt[i]);
    // ---- last-block election (syncthreads drains the atomics above) ------
    __syncthreads();
    if (threadIdx.x == 0) {
        __threadfence();
        slast = (atomicAdd(&flags[2], 1u) == (unsigned)gridDim.x - 1u) ? 1u : 0u;
    }
    __syncthreads();
    if (!slast) return;
    // ---- exclusive scan over nb counts (this block only) ------------------
    const int t = threadIdx.x;
    const int L = (nb + HIST_THREADS - 1) / HIST_THREADS;
    unsigned local = 0u;
    for (int i = 0; i < L; ++i) {
        int idx = t * L + i;
        if (idx < nb) local += atomicAdd(&gcnt[idx], 0u);   // coherent read
    }
    s[t] = local;
    __syncthreads();
    for (int off = 1; off < HIST_THREADS; off <<= 1) {
        unsigned v = (t >= off) ? s[t - off] : 0u;
        __syncthreads();
        s[t] += v;
        __syncthreads();
    }
    unsigned run = s[t] - local;
    for (int i = 0; i < L; ++i) {
        int idx = t * L + i;
        if (idx < nb) {
            unsigned g = atomicAdd(&gcnt[idx], 0u);          // coherent read
            boffs[idx] = run; cursor[idx] = run; run += g;
        }
    }
}

// ---------------------------------------------------------------------------
// FUSED kernel (round-7 winner, unchanged). Blocks [0,NBIN): binning
// (LDS-staged scatter of packed dl|src into bucket-grouped order). Blocks
// [NBIN,NBIN+NGEMM): edge-MLP GEMM (P = G@W^T; Q' = RSC@W^T - b).
// __launch_bounds__(512,4): round-4 lesson — (512,8) forced VGPR 52->32 and
// spilled the per-lane w[64] array to scratch (FETCH 16->321 MB, 48->131us).
// Round-9/10 lessons: do NOT fuse phases via coop grid.sync (L2 coherency
// tax ~270us) and do NOT give binning a dedicated wide grid (flush overhead
// scales with blocks*nb).
// ---------------------------------------------------------------------------
__global__ __launch_bounds__(FUSE_THREADS, 4)
void binning_gemm_kernel(const void* __restrict__ srcp, const void* __restrict__ dstp,
                         unsigned* __restrict__ cursor, unsigned* __restrict__ binned,
                         const unsigned* __restrict__ flags, int n_edges, int nb,
                         int depth,
                         const void* __restrict__ Gp, const void* __restrict__ Rp,
                         const void* __restrict__ Wp, const void* __restrict__ bp,
                         void* __restrict__ PQ, int n_nodes) {
    extern __shared__ unsigned lds[];
    if (blockIdx.x < NBIN) {
        // ------------------------- binning path ---------------------------
        unsigned* lcnt = lds;               // [nb]
        unsigned* stage = lds + nb;         // [nb*depth]
        for (int i = threadIdx.x; i < nb; i += blockDim.x) lcnt[i] = 0u;
        __syncthreads();
        const unsigned i64 = flags[1];
        const int chunk = (n_edges + NBIN - 1) / NBIN;
        const int e0 = blockIdx.x * chunk;
        const int e1 = min(e0 + chunk, n_edges);
        for (int e = e0 + threadIdx.x; e < e1; e += blockDim.x) {
            int s, d;
            if (i64) {
                s = (int)((const long long*)srcp)[e];
                d = (int)((const long long*)dstp)[e];
            } else {
                s = ((const int*)srcp)[e];
                d = ((const int*)dstp)[e];
            }
            const int bkt = d >> 6;
            const unsigned pk = ((unsigned)(d & 63) << 26) | (unsigned)s;
            unsigned pos = atomicAdd(&lcnt[bkt], 1u);
            if ((int)pos < depth) {
                stage[bkt * depth + (int)pos] = pk;
            } else {
                unsigned g = atomicAdd(&cursor[bkt], 1u);
                binned[g] = pk;
            }
        }
        __syncthreads();
        for (int bkt = threadIdx.x; bkt < nb; bkt += blockDim.x) {
            int k = min((int)lcnt[bkt], depth);
            if (k > 0) {
                unsigned base = atomicAdd(&cursor[bkt], (unsigned)k);
                for (int i = 0; i < k; ++i) binned[base + i] = stage[bkt * depth + i];
            }
        }
    } else {
        // -------------------------- gemm path -----------------------------
        const unsigned f32 = flags[0];
        const int lane = threadIdx.x & 63;
        const int waveInBlk = threadIdx.x >> 6;
        const int gwave = (blockIdx.x - NBIN) * 8 + waveInBlk;
        const int nwaves = NGEMM * 8;
        const int n_rows = 2 * n_nodes;
        const int ngroups = (n_rows + 3) / 4;

        float* ldsb = (float*)lds;                        // 8KB of the dyn LDS
        float* slot = &ldsb[waveInBlk * 4 * NCH];

        float w[NCH];
        float bias;
        if (f32) {
            const float* Wf = (const float*)Wp;
            #pragma unroll
            for (int k = 0; k < NCH; ++k) w[k] = Wf[lane * NCH + k];
            bias = ((const float*)bp)[lane];
        } else {
            const __hip_bfloat16* Wh = (const __hip_bfloat16*)Wp;
            #pragma unroll
            for (int k = 0; k < NCH; ++k) w[k] = __bfloat162float(Wh[lane * NCH + k]);
            bias = __bfloat162float(((const __hip_bfloat16*)bp)[lane]);
        }

        const int niter = (ngroups + nwaves - 1) / nwaves;
        for (int it = 0; it < niter; ++it) {
            const int grp = gwave + it * nwaves;
            const bool gvalid = (grp < ngroups);
            const int m0 = grp * 4;
            if (gvalid) {
                const int myrow = m0 + (lane >> 4);
                const int col = (lane & 15) * 4;
                float x0 = 0.f, x1 = 0.f, x2 = 0.f, x3 = 0.f;
                if (myrow < n_rows) {
                    const bool isQ = (myrow >= n_nodes);
                    const int r = isQ ? (myrow - n_nodes) : myrow;
                    const void* inp = isQ ? Rp : Gp;
                    if (f32) {
                        float4 v = *(const float4*)((const float*)inp +
                                                    (size_t)r * NCH + col);
                        x0 = v.x; x1 = v.y; x2 = v.z; x3 = v.w;
                    } else {
                        ushort4 v = *(const ushort4*)((const unsigned short*)inp +
                                                      (size_t)r * NCH + col);
                        x0 = __bfloat162float(*(__hip_bfloat16*)&v.x);
                        x1 = __bfloat162float(*(__hip_bfloat16*)&v.y);
                        x2 = __bfloat162float(*(__hip_bfloat16*)&v.z);
                        x3 = __bfloat162float(*(__hip_bfloat16*)&v.w);
                    }
                }
                const int sb = (lane >> 4) * NCH + col;
                slot[sb + 0] = x0; slot[sb + 1] = x1;
                slot[sb + 2] = x2; slot[sb + 3] = x3;
            }
            __syncthreads();
            if (gvalid) {
                #pragma unroll
                for (int rr = 0; rr < 4; ++rr) {
                    const int m = m0 + rr;
                    if (m < n_rows) {
                        float a0 = 0.f, a1 = 0.f, a2 = 0.f, a3 = 0.f;
                        const float4* r4 = (const float4*)(slot + rr * NCH);
                        #pragma unroll
                        for (int q = 0; q < 16; ++q) {
                            float4 rv = r4[q];
                            a0 = fmaf(rv.x, w[4 * q + 0], a0);
                            a1 = fmaf(rv.y, w[4 * q + 1], a1);
                            a2 = fmaf(rv.z, w[4 * q + 2], a2);
                            a3 = fmaf(rv.w, w[4 * q + 3], a3);
                        }
                        float acc = (a0 + a1) + (a2 + a3);
                        if (m >= n_nodes) acc -= bias;       // Q' = RSC@W^T - b
                        if (f32) ((float*)PQ)[(size_t)m * NCH + lane] = acc;
                        else ((__hip_bfloat16*)PQ)[(size_t)m * NCH + lane] =
                                 __float2bfloat16(acc);
                    }
                }
            }
            __syncthreads();
        }
    }
}

// ---------------------------------------------------------------------------
// FUSED bucket sort + node aggregation (round-7 winner, unchanged):
// block = bucket of 64 dst nodes. Stage packed edges in LDS, in-LDS counting
// sort into per-node runs, then wave-per-node gather with register
// accumulation (NO LDS accumulators — round-1 lesson). Overflow (>NB_CAP)
// falls back to a per-node filter scan over global binned (rare).
// ---------------------------------------------------------------------------
__global__ __launch_bounds__(512)
void bucket_node_kernel(const unsigned* __restrict__ binned,
                        const unsigned* __restrict__ boffs,
                        const unsigned* __restrict__ gcnt,
                        const void* __restrict__ PQ,
                        const unsigned* __restrict__ flags,
                        void* __restrict__ outp, int n_nodes) {
    __shared__ unsigned scnt[SPAN];
    __shared__ unsigned soff[SPAN];
    __shared__ unsigned cur[SPAN];
    __shared__ unsigned dext[SPAN];
    __shared__ unsigned stage[NB_CAP];
    __shared__ unsigned sorted[NB_CAP];

    const int b = blockIdx.x;
    const int tid = threadIdx.x;
    const int estart = (int)boffs[b];
    const int count = (int)gcnt[b];
    const int lim = (count < NB_CAP) ? count : NB_CAP;

    if (tid < SPAN) { scnt[tid] = 0u; dext[tid] = 0u; }
    __syncthreads();

    for (int i = tid; i < count; i += 512) {
        const unsigned pk = binned[estart + i];
        if (i < NB_CAP) { stage[i] = pk; atomicAdd(&scnt[pk >> 26], 1u); }
        else atomicAdd(&dext[pk >> 26], 1u);
    }
    __syncthreads();

    if (tid == 0) {
        unsigned run = 0u;
        #pragma unroll
        for (int i = 0; i < SPAN; ++i) { soff[i] = run; cur[i] = run; run += scnt[i]; }
    }
    __syncthreads();

    for (int i = tid; i < lim; i += 512) {
        const unsigned pk = stage[i];
        const unsigned pos = atomicAdd(&cur[pk >> 26], 1u);
        sorted[pos] = pk & 0x03FFFFFFu;
    }
    __syncthreads();

    const unsigned f32 = flags[0];
    const int lane = tid & 63;
    const int wid = tid >> 6;
    const float* Pf = (const float*)PQ;
    const unsigned short* Ph = (const unsigned short*)PQ;

    for (int nn = wid; nn < SPAN; nn += 8) {
        const int n = b * SPAN + nn;
        if (n >= n_nodes) break;
        float q;
        if (f32) q = Pf[(size_t)(n_nodes + n) * NCH + lane];
        else {
            unsigned short h = Ph[(size_t)(n_nodes + n) * NCH + lane];
            q = __bfloat162float(*(__hip_bfloat16*)&h);
        }
        const int s0i = (int)soff[nn];
        const int scn = (int)scnt[nn];
        float vmax = 0.0f, vsum = 0.0f;
        int j = 0;
        for (; j + 4 <= scn; j += 4) {
            const int e0 = (int)sorted[s0i + j];
            const int e1 = (int)sorted[s0i + j + 1];
            const int e2 = (int)sorted[s0i + j + 2];
            const int e3 = (int)sorted[s0i + j + 3];
            float p0, p1, p2, p3;
            if (f32) {
                p0 = Pf[(size_t)e0 * NCH + lane];
                p1 = Pf[(size_t)e1 * NCH + lane];
                p2 = Pf[(size_t)e2 * NCH + lane];
                p3 = Pf[(size_t)e3 * NCH + lane];
            } else {
                unsigned short h0 = Ph[(size_t)e0 * NCH + lane];
                unsigned short h1 = Ph[(size_t)e1 * NCH + lane];
                unsigned short h2 = Ph[(size_t)e2 * NCH + lane];
                unsigned short h3 = Ph[(size_t)e3 * NCH + lane];
                p0 = __bfloat162float(*(__hip_bfloat16*)&h0);
                p1 = __bfloat162float(*(__hip_bfloat16*)&h1);
                p2 = __bfloat162float(*(__hip_bfloat16*)&h2);
                p3 = __bfloat162float(*(__hip_bfloat16*)&h3);
            }
            const float v0 = fmaxf(p0 - q, 0.0f);
            const float v1 = fmaxf(p1 - q, 0.0f);
            const float v2 = fmaxf(p2 - q, 0.0f);
            const float v3 = fmaxf(p3 - q, 0.0f);
            vmax = fmaxf(fmaxf(vmax, v0), fmaxf(v1, fmaxf(v2, v3)));
            vsum += (v0 + v1) + (v2 + v3);
        }
        for (; j < scn; ++j) {
            const int e = (int)sorted[s0i + j];
            float p;
            if (f32) p = Pf[(size_t)e * NCH + lane];
            else {
                unsigned short h = Ph[(size_t)e * NCH + lane];
                p = __bfloat162float(*(__hip_bfloat16*)&h);
            }
            const float v = fmaxf(p - q, 0.0f);
            vmax = fmaxf(vmax, v);
            vsum += v;
        }
        for (int i = NB_CAP; i < count; ++i) {
            const unsigned pk = binned[estart + i];
            if ((int)(pk >> 26) == nn) {
                const int e = (int)(pk & 0x03FFFFFFu);
                float p;
                if (f32) p = Pf[(size_t)e * NCH + lane];
                else {
                    unsigned short h = Ph[(size_t)e * NCH + lane];
                    p = __bfloat162float(*(__hip_bfloat16*)&h);
                }
                const float v = fmaxf(p - q, 0.0f);
                vmax = fmaxf(vmax, v);
                vsum += v;
            }
        }
        const int deg = scn + (int)dext[nn];
        const float avg = vsum / (float)(deg > 0 ? deg : 1);
        if (f32) {
            float* out = (float*)outp;
            out[(size_t)n * 2 * NCH + lane] = vmax;
            out[(size_t)n * 2 * NCH + NCH + lane] = avg;
        } else {
            __hip_bfloat16* out = (__hip_bfloat16*)outp;
            out[(size_t)n * 2 * NCH + lane] = __float2bfloat16(vmax);
            out[(size_t)n * 2 * NCH + NCH + lane] = __float2bfloat16(avg);
        }
    }
}

extern "C" void kernel_launch(void* const* d_in, const int* in_sizes, int n_in,
                              void* d_out, int out_size, void* d_ws, size_t ws_size,
                              hipStream_t stream) {
    const void* G = d_in[0];
    const void* RSC = d_in[1];
    const void* src = d_in[2];
    const void* dst = d_in[3];
    const void* W = d_in[4];
    const void* b = d_in[5];

    const int n_nodes = in_sizes[0] / NCH;
    const int n_edges = in_sizes[2];
    const int nb = (n_nodes + SPAN - 1) / SPAN;

    // ws layout (bytes): [flags 256][binned 4E][boffs 4nb][cursor 4nb]
    //                    [gcnt 4nb][PQ dtype*64*2N]
    char* ws = (char*)d_ws;
    unsigned* flags = (unsigned*)ws;
    size_t off = 256;
    unsigned* binned = (unsigned*)(ws + off);
    off += (((size_t)n_edges * 4 + 255) / 256) * 256;
    unsigned* boffs = (unsigned*)(ws + off);
    off += (((size_t)nb * 4 + 255) / 256) * 256;
    unsigned* cursor = (unsigned*)(ws + off);
    off += (((size_t)nb * 4 + 255) / 256) * 256;
    unsigned* gcnt = (unsigned*)(ws + off);
    off += (((size_t)nb * 4 + 255) / 256) * 256;
    void* PQ = (void*)(ws + off);                   // fp32 or bf16 per flags[0]

    const int n_g_probe = (in_sizes[0] < 8192) ? in_sizes[0] : 8192;
    const int n_idx_probe = (n_edges < 8192) ? n_edges : 8192;

    detect_init_kernel<<<64, 256, 0, stream>>>((const unsigned short*)G, n_g_probe,
                                               (const unsigned*)src, n_idx_probe,
                                               flags, gcnt, nb);

    // hist + last-block scan epilogue (writes boffs + cursor)
    bucket_hist_kernel<<<HIST_BLOCKS, HIST_THREADS, (size_t)nb * 4, stream>>>(
        dst, gcnt, flags, boffs, cursor, n_edges, nb);

    // depth sized for ~37.5K LDS -> 4 blocks/CU possible by LDS.
    int depth = 9728 / nb - 1;
    if (depth > 19) depth = 19;
    if (depth < 4) depth = 4;
    size_t bin_lds = (size_t)nb * (depth + 1) * 4;
    const size_t gemm_lds = (size_t)(FUSE_THREADS / 64) * 4 * NCH * 4;  // 8 KB
    if (bin_lds < gemm_lds) bin_lds = gemm_lds;

    binning_gemm_kernel<<<NBIN + NGEMM, FUSE_THREADS, bin_lds, stream>>>(
        src, dst, cursor, binned, flags, n_edges, nb, depth,
        G, RSC, W, b, PQ, n_nodes);

    bucket_node_kernel<<<nb, 512, 0, stream>>>(binned, boffs, gcnt, PQ, flags,
                                               d_out, n_nodes);
}

// Round 12
// 179.036 us; speedup vs baseline: 2.5922x; 1.0294x over previous
//
#include <hip/hip_runtime.h>
#include <hip/hip_bf16.h>

#define NCH 64
#define SPAN 64            // dst nodes per bucket (dl fits in 6 bits)
#define NBIN 256           // binning blocks (fused kernel, low half)
#define NGEMM 768          // gemm blocks   (fused kernel, high half)
#define FUSE_THREADS 512   // 8 waves/block
#define NB_CAP 1536        // bucket slot capacity AND LDS stage capacity
                           // (lambda~1023, sigma~32 -> P(>1536) ~ 0 at 16sigma;
                           //  overflow list keeps adversarial inputs correct)

// ---------------------------------------------------------------------------
// Block 0: dtype detection (flags[0]=fp32?, flags[1]=int64?) + zero the
// overflow cursor flags[2]. Other blocks: zero gcnt (ws poisoned 0xAA).
// Round-12: gcnt doubles as the bucket placement cursor (fixed-capacity
// slots), which deletes the whole hist+scan pass (4 -> 3 dispatches).
// ---------------------------------------------------------------------------
__global__ void detect_init_kernel(const unsigned short* __restrict__ gp, int n16,
                                   const unsigned* __restrict__ ip, int niw,
                                   unsigned* __restrict__ flags,
                                   unsigned* __restrict__ gcnt, int nb) {
    if (blockIdx.x == 0) {
        __shared__ unsigned se, so;
        if (threadIdx.x == 0) { se = 0u; so = 0u; flags[2] = 0u; }
        __syncthreads();
        unsigned le = 0u, lo = 0u;
        // fp32 viewed as shorts: ~12.5% show "bf16 exponent" >= 0xC0 (|x|>=2^65).
        // Genuine bf16 N(0,1): none.
        for (int i = threadIdx.x; i < n16; i += blockDim.x) {
            unsigned ex = (unsigned)((gp[i] >> 7) & 0xFFu);
            if (ex >= 0xC0u) le++;
        }
        // int64 ids (<2^31): every odd 32-bit word is 0. int32 ids: not.
        for (int i = threadIdx.x; i < niw; i += blockDim.x) {
            if ((i & 1) && ip[i] != 0u) lo++;
        }
        atomicAdd(&se, le);
        atomicAdd(&so, lo);
        __syncthreads();
        if (threadIdx.x == 0) {
            flags[0] = (se > 50u) ? 1u : 0u;
            flags[1] = (so < 50u) ? 1u : 0u;
        }
    } else {
        const int stride = (gridDim.x - 1) * blockDim.x;
        for (int i = (blockIdx.x - 1) * blockDim.x + threadIdx.x; i < nb; i += stride)
            gcnt[i] = 0u;
    }
}

// ---------------------------------------------------------------------------
// FUSED kernel. Blocks [0,NBIN): binning into FIXED-CAPACITY bucket slots
// (binned[b*NB_CAP + atomicAdd(&gcnt[b],..)]) — no hist, no scan, no boffs.
// LDS staging (depth/bucket) keeps flushes as contiguous runs. Entries past
// NB_CAP go to a global overflow list (ovbuf, cursor flags[2]) — ~never for
// uniform data, correct for any skew. Blocks [NBIN,NBIN+NGEMM): edge-MLP
// GEMM (P = G@W^T; Q' = RSC@W^T - b), spatially overlapped (round-7 winner).
// __launch_bounds__(512,4): round-4 lesson — (512,8) spills w[64] to scratch.
// Round-9/10 lessons: no coop grid.sync; no dedicated wide binning grid.
// ---------------------------------------------------------------------------
__global__ __launch_bounds__(FUSE_THREADS, 4)
void binning_gemm_kernel(const void* __restrict__ srcp, const void* __restrict__ dstp,
                         unsigned* __restrict__ gcnt, unsigned* __restrict__ binned,
                         unsigned long long* __restrict__ ovbuf,
                         unsigned* __restrict__ flags, int n_edges, int nb,
                         int depth,
                         const void* __restrict__ Gp, const void* __restrict__ Rp,
                         const void* __restrict__ Wp, const void* __restrict__ bp,
                         void* __restrict__ PQ, int n_nodes) {
    extern __shared__ unsigned lds[];
    if (blockIdx.x < NBIN) {
        // ------------------------- binning path ---------------------------
        unsigned* lcnt = lds;               // [nb]
        unsigned* stage = lds + nb;         // [nb*depth]
        for (int i = threadIdx.x; i < nb; i += blockDim.x) lcnt[i] = 0u;
        __syncthreads();
        const unsigned i64 = flags[1];
        const int chunk = (n_edges + NBIN - 1) / NBIN;
        const int e0 = blockIdx.x * chunk;
        const int e1 = min(e0 + chunk, n_edges);
        for (int e = e0 + threadIdx.x; e < e1; e += blockDim.x) {
            int s, d;
            if (i64) {
                s = (int)((const long long*)srcp)[e];
                d = (int)((const long long*)dstp)[e];
            } else {
                s = ((const int*)srcp)[e];
                d = ((const int*)dstp)[e];
            }
            const int bkt = d >> 6;
            const unsigned pk = ((unsigned)(d & 63) << 26) | (unsigned)s;
            unsigned pos = atomicAdd(&lcnt[bkt], 1u);
            if ((int)pos < depth) {
                stage[bkt * depth + (int)pos] = pk;
            } else {
                unsigned g = atomicAdd(&gcnt[bkt], 1u);
                if (g < NB_CAP) {
                    binned[bkt * NB_CAP + g] = pk;
                } else {
                    unsigned oi = atomicAdd(&flags[2], 1u);
                    ovbuf[oi] = ((unsigned long long)(unsigned)d << 32) |
                                (unsigned long long)(unsigned)s;
                }
            }
        }
        __syncthreads();
        for (int bkt = threadIdx.x; bkt < nb; bkt += blockDim.x) {
            int k = min((int)lcnt[bkt], depth);
            if (k > 0) {
                unsigned base = atomicAdd(&gcnt[bkt], (unsigned)k);
                for (int i = 0; i < k; ++i) {
                    const unsigned pk = stage[bkt * depth + i];
                    const unsigned pos = base + (unsigned)i;
                    if (pos < NB_CAP) {
                        binned[bkt * NB_CAP + pos] = pk;
                    } else {
                        const unsigned d = (unsigned)(bkt * SPAN) + (pk >> 26);
                        unsigned oi = atomicAdd(&flags[2], 1u);
                        ovbuf[oi] = ((unsigned long long)d << 32) |
                                    (unsigned long long)(pk & 0x03FFFFFFu);
                    }
                }
            }
        }
    } else {
        // -------------------------- gemm path -----------------------------
        const unsigned f32 = flags[0];
        const int lane = threadIdx.x & 63;
        const int waveInBlk = threadIdx.x >> 6;
        const int gwave = (blockIdx.x - NBIN) * 8 + waveInBlk;
        const int nwaves = NGEMM * 8;
        const int n_rows = 2 * n_nodes;
        const int ngroups = (n_rows + 3) / 4;

        float* ldsb = (float*)lds;                        // 8KB of the dyn LDS
        float* slot = &ldsb[waveInBlk * 4 * NCH];

        float w[NCH];
        float bias;
        if (f32) {
            const float* Wf = (const float*)Wp;
            #pragma unroll
            for (int k = 0; k < NCH; ++k) w[k] = Wf[lane * NCH + k];
            bias = ((const float*)bp)[lane];
        } else {
            const __hip_bfloat16* Wh = (const __hip_bfloat16*)Wp;
            #pragma unroll
            for (int k = 0; k < NCH; ++k) w[k] = __bfloat162float(Wh[lane * NCH + k]);
            bias = __bfloat162float(((const __hip_bfloat16*)bp)[lane]);
        }

        const int niter = (ngroups + nwaves - 1) / nwaves;
        for (int it = 0; it < niter; ++it) {
            const int grp = gwave + it * nwaves;
            const bool gvalid = (grp < ngroups);
            const int m0 = grp * 4;
            if (gvalid) {
                const int myrow = m0 + (lane >> 4);
                const int col = (lane & 15) * 4;
                float x0 = 0.f, x1 = 0.f, x2 = 0.f, x3 = 0.f;
                if (myrow < n_rows) {
                    const bool isQ = (myrow >= n_nodes);
                    const int r = isQ ? (myrow - n_nodes) : myrow;
                    const void* inp = isQ ? Rp : Gp;
                    if (f32) {
                        float4 v = *(const float4*)((const float*)inp +
                                                    (size_t)r * NCH + col);
                        x0 = v.x; x1 = v.y; x2 = v.z; x3 = v.w;
                    } else {
                        ushort4 v = *(const ushort4*)((const unsigned short*)inp +
                                                      (size_t)r * NCH + col);
                        x0 = __bfloat162float(*(__hip_bfloat16*)&v.x);
                        x1 = __bfloat162float(*(__hip_bfloat16*)&v.y);
                        x2 = __bfloat162float(*(__hip_bfloat16*)&v.z);
                        x3 = __bfloat162float(*(__hip_bfloat16*)&v.w);
                    }
                }
                const int sb = (lane >> 4) * NCH + col;
                slot[sb + 0] = x0; slot[sb + 1] = x1;
                slot[sb + 2] = x2; slot[sb + 3] = x3;
            }
            __syncthreads();
            if (gvalid) {
                #pragma unroll
                for (int rr = 0; rr < 4; ++rr) {
                    const int m = m0 + rr;
                    if (m < n_rows) {
                        float a0 = 0.f, a1 = 0.f, a2 = 0.f, a3 = 0.f;
                        const float4* r4 = (const float4*)(slot + rr * NCH);
                        #pragma unroll
                        for (int q = 0; q < 16; ++q) {
                            float4 rv = r4[q];
                            a0 = fmaf(rv.x, w[4 * q + 0], a0);
                            a1 = fmaf(rv.y, w[4 * q + 1], a1);
                            a2 = fmaf(rv.z, w[4 * q + 2], a2);
                            a3 = fmaf(rv.w, w[4 * q + 3], a3);
                        }
                        float acc = (a0 + a1) + (a2 + a3);
                        if (m >= n_nodes) acc -= bias;       // Q' = RSC@W^T - b
                        if (f32) ((float*)PQ)[(size_t)m * NCH + lane] = acc;
                        else ((__hip_bfloat16*)PQ)[(size_t)m * NCH + lane] =
                                 __float2bfloat16(acc);
                    }
                }
            }
            __syncthreads();
        }
    }
}

// ---------------------------------------------------------------------------
// FUSED bucket sort + node aggregation (round-7 winner; estart -> b*NB_CAP):
// block = bucket of 64 dst nodes. Stage packed edges in LDS, in-LDS counting
// sort into per-node runs, then wave-per-node gather with register
// accumulation (NO LDS accumulators — round-1 lesson). Overflow entries live
// in the global ovbuf list (count flags[2], ~0 for uniform data) and are
// filter-scanned per node.
// ---------------------------------------------------------------------------
__global__ __launch_bounds__(512)
void bucket_node_kernel(const unsigned* __restrict__ binned,
                        const unsigned* __restrict__ gcnt,
                        const unsigned long long* __restrict__ ovbuf,
                        const void* __restrict__ PQ,
                        const unsigned* __restrict__ flags,
                        void* __restrict__ outp, int n_nodes) {
    __shared__ unsigned scnt[SPAN];
    __shared__ unsigned soff[SPAN];
    __shared__ unsigned cur[SPAN];
    __shared__ unsigned stage[NB_CAP];
    __shared__ unsigned sorted[NB_CAP];

    const int b = blockIdx.x;
    const int tid = threadIdx.x;
    const int estart = b * NB_CAP;
    const int gc = (int)gcnt[b];
    const int count = (gc < NB_CAP) ? gc : NB_CAP;   // direct-region entries
    const int n_ov = (int)flags[2];                  // global overflow count

    if (tid < SPAN) scnt[tid] = 0u;
    __syncthreads();

    for (int i = tid; i < count; i += 512) {
        const unsigned pk = binned[estart + i];
        stage[i] = pk;
        atomicAdd(&scnt[pk >> 26], 1u);
    }
    __syncthreads();

    if (tid == 0) {
        unsigned run = 0u;
        #pragma unroll
        for (int i = 0; i < SPAN; ++i) { soff[i] = run; cur[i] = run; run += scnt[i]; }
    }
    __syncthreads();

    for (int i = tid; i < count; i += 512) {
        const unsigned pk = stage[i];
        const unsigned pos = atomicAdd(&cur[pk >> 26], 1u);
        sorted[pos] = pk & 0x03FFFFFFu;
    }
    __syncthreads();

    const unsigned f32 = flags[0];
    const int lane = tid & 63;
    const int wid = tid >> 6;
    const float* Pf = (const float*)PQ;
    const unsigned short* Ph = (const unsigned short*)PQ;

    for (int nn = wid; nn < SPAN; nn += 8) {
        const int n = b * SPAN + nn;
        if (n >= n_nodes) break;
        float q;
        if (f32) q = Pf[(size_t)(n_nodes + n) * NCH + lane];
        else {
            unsigned short h = Ph[(size_t)(n_nodes + n) * NCH + lane];
            q = __bfloat162float(*(__hip_bfloat16*)&h);
        }
        const int s0i = (int)soff[nn];
        const int scn = (int)scnt[nn];
        float vmax = 0.0f, vsum = 0.0f;
        int j = 0;
        for (; j + 4 <= scn; j += 4) {
            const int e0 = (int)sorted[s0i + j];
            const int e1 = (int)sorted[s0i + j + 1];
            const int e2 = (int)sorted[s0i + j + 2];
            const int e3 = (int)sorted[s0i + j + 3];
            float p0, p1, p2, p3;
            if (f32) {
                p0 = Pf[(size_t)e0 * NCH + lane];
                p1 = Pf[(size_t)e1 * NCH + lane];
                p2 = Pf[(size_t)e2 * NCH + lane];
                p3 = Pf[(size_t)e3 * NCH + lane];
            } else {
                unsigned short h0 = Ph[(size_t)e0 * NCH + lane];
                unsigned short h1 = Ph[(size_t)e1 * NCH + lane];
                unsigned short h2 = Ph[(size_t)e2 * NCH + lane];
                unsigned short h3 = Ph[(size_t)e3 * NCH + lane];
                p0 = __bfloat162float(*(__hip_bfloat16*)&h0);
                p1 = __bfloat162float(*(__hip_bfloat16*)&h1);
                p2 = __bfloat162float(*(__hip_bfloat16*)&h2);
                p3 = __bfloat162float(*(__hip_bfloat16*)&h3);
            }
            const float v0 = fmaxf(p0 - q, 0.0f);
            const float v1 = fmaxf(p1 - q, 0.0f);
            const float v2 = fmaxf(p2 - q, 0.0f);
            const float v3 = fmaxf(p3 - q, 0.0f);
            vmax = fmaxf(fmaxf(vmax, v0), fmaxf(v1, fmaxf(v2, v3)));
            vsum += (v0 + v1) + (v2 + v3);
        }
        for (; j < scn; ++j) {
            const int e = (int)sorted[s0i + j];
            float p;
            if (f32) p = Pf[(size_t)e * NCH + lane];
            else {
                unsigned short h = Ph[(size_t)e * NCH + lane];
                p = __bfloat162float(*(__hip_bfloat16*)&h);
            }
            const float v = fmaxf(p - q, 0.0f);
            vmax = fmaxf(vmax, v);
            vsum += v;
        }
        // overflow list (global; ~empty for uniform data): filter by node id
        int ext = 0;
        for (int i = 0; i < n_ov; ++i) {
            const unsigned long long ov = ovbuf[i];      // wave-uniform load
            const int d = (int)(ov >> 32);
            if (d == n) {
                const int e = (int)(ov & 0x03FFFFFFu);
                float p;
                if (f32) p = Pf[(size_t)e * NCH + lane];
                else {
                    unsigned short h = Ph[(size_t)e * NCH + lane];
                    p = __bfloat162float(*(__hip_bfloat16*)&h);
                }
                const float v = fmaxf(p - q, 0.0f);
                vmax = fmaxf(vmax, v);
                vsum += v;
                ext++;
            }
        }
        const int deg = scn + ext;
        const float avg = vsum / (float)(deg > 0 ? deg : 1);
        if (f32) {
            float* out = (float*)outp;
            out[(size_t)n * 2 * NCH + lane] = vmax;
            out[(size_t)n * 2 * NCH + NCH + lane] = avg;
        } else {
            __hip_bfloat16* out = (__hip_bfloat16*)outp;
            out[(size_t)n * 2 * NCH + lane] = __float2bfloat16(vmax);
            out[(size_t)n * 2 * NCH + NCH + lane] = __float2bfloat16(avg);
        }
    }
}

extern "C" void kernel_launch(void* const* d_in, const int* in_sizes, int n_in,
                              void* d_out, int out_size, void* d_ws, size_t ws_size,
                              hipStream_t stream) {
    const void* G = d_in[0];
    const void* RSC = d_in[1];
    const void* src = d_in[2];
    const void* dst = d_in[3];
    const void* W = d_in[4];
    const void* b = d_in[5];

    const int n_nodes = in_sizes[0] / NCH;
    const int n_edges = in_sizes[2];
    const int nb = (n_nodes + SPAN - 1) / SPAN;

    // ws layout (bytes): [flags 256][binned 4*nb*NB_CAP][ovbuf 8E]
    //                    [gcnt 4nb][PQ dtype*64*2N]
    char* ws = (char*)d_ws;
    unsigned* flags = (unsigned*)ws;
    size_t off = 256;
    unsigned* binned = (unsigned*)(ws + off);
    off += (((size_t)nb * NB_CAP * 4 + 255) / 256) * 256;
    unsigned long long* ovbuf = (unsigned long long*)(ws + off);
    off += (((size_t)n_edges * 8 + 255) / 256) * 256;
    unsigned* gcnt = (unsigned*)(ws + off);
    off += (((size_t)nb * 4 + 255) / 256) * 256;
    void* PQ = (void*)(ws + off);                   // fp32 or bf16 per flags[0]

    const int n_g_probe = (in_sizes[0] < 8192) ? in_sizes[0] : 8192;
    const int n_idx_probe = (n_edges < 8192) ? n_edges : 8192;

    detect_init_kernel<<<64, 256, 0, stream>>>((const unsigned short*)G, n_g_probe,
                                               (const unsigned*)src, n_idx_probe,
                                               flags, gcnt, nb);

    // depth sized for ~37.5K LDS -> 4 blocks/CU possible by LDS.
    int depth = 9728 / nb - 1;
    if (depth > 19) depth = 19;
    if (depth < 4) depth = 4;
    size_t bin_lds = (size_t)nb * (depth + 1) * 4;
    const size_t gemm_lds = (size_t)(FUSE_THREADS / 64) * 4 * NCH * 4;  // 8 KB
    if (bin_lds < gemm_lds) bin_lds = gemm_lds;

    binning_gemm_kernel<<<NBIN + NGEMM, FUSE_THREADS, bin_lds, stream>>>(
        src, dst, gcnt, binned, ovbuf, flags, n_edges, nb, depth,
        G, RSC, W, b, PQ, n_nodes);

    bucket_node_kernel<<<nb, 512, 0, stream>>>(binned, gcnt, ovbuf, PQ, flags,
                                               d_out, n_nodes);
}